// Round 5
// baseline (170.108 us; speedup 1.0000x reference)
//
#include <hip/hip_runtime.h>
#include <stdint.h>
#include <math.h>

// Problem constants
#define NV 32      // num_vari (groups)
#define NB 4096    // batch
#define NK 256     // 2*dim_per_vari (contraction)
#define NO 256     // dim_to (output features)

typedef __bf16 bf16x8 __attribute__((ext_vector_type(8)));
typedef float  f32x4  __attribute__((ext_vector_type(4)));

__device__ __forceinline__ f32x4 mfma16(bf16x8 a, bf16x8 b, f32x4 c) {
    return __builtin_amdgcn_mfma_f32_16x16x32_bf16(a, b, c, 0, 0, 0);
}

__device__ __forceinline__ float softplus_f(float z) {
    // stable: max(z,0) + log(1+exp(-|z|)); fast-math err ~1e-3 << 1.055 threshold
    return fmaxf(z, 0.0f) + __logf(1.0f + __expf(-fabsf(z)));
}

// ---------------------------------------------------------------------------
// prep: W[v][k][o] fp32  ->  Wt[v][o][k] bf16  (transpose + convert, 4 MB)
__global__ __launch_bounds__(256)
void prep_wt_kernel(const float* __restrict__ w, __bf16* __restrict__ wt) {
    const int id = blockIdx.x * 256 + threadIdx.x;   // 32*256*32 = 262144
    const int o  = id & 255;
    const int kc = (id >> 8) & 31;    // 8-k chunk
    const int v  = id >> 13;
    const float* src = w + ((size_t)v * NK + (size_t)kc * 8) * NO + o;
    bf16x8 r;
#pragma unroll
    for (int j = 0; j < 8; ++j) r[j] = (__bf16)src[(size_t)j * NO];
    *(bf16x8*)(wt + ((size_t)v * NO + o) * NK + kc * 8) = r;
}

// ---------------------------------------------------------------------------
// main: out[v][b][o] = softplus( x[v][b][:] . Wt[v][o][:] + 256*bias[v][o] )
//
// NO LDS, NO barriers. Per wave: 32 o-columns of Wt held in 64 VGPRs (read
// once from L2), then stream 4 m-tiles of 16 batch rows: x HBM->VGPR in
// B-fragment layout, cvt fp32->bf16, 16 MFMA, softplus, store. Waves
// free-run; TLP (12 waves/CU) + 16KB in-flight loads/wave hide all latency.
__global__ __launch_bounds__(256, 3)
void mv_dense_kernel(const float* __restrict__ x, const __bf16* __restrict__ wt,
                     const float* __restrict__ bias, float* __restrict__ out) {
    const int t    = threadIdx.x;
    const int w    = t >> 6;      // wave 0..3
    const int lane = t & 63;
    const int lr   = lane & 15;   // fragment row (batch) / W row (o)
    const int lg   = lane >> 4;   // k-group (8 contiguous k)

    // XCD-chunked swizzle: 4096 blocks = 8 XCD x 512; each XCD owns 4 v's
    // (Wt slice 512 KB in its L2); oh-pairs of the same m-tile are adjacent.
    const int bid = blockIdx.x;
    const int lb  = (bid & 7) * 512 + (bid >> 3);
    const int v   = lb >> 7;          // 0..31
    const int mb  = (lb & 127) >> 1;  // 0..63 -> 64 batch rows each
    const int oh  = lb & 1;           // o-half

    const int obase = oh * 128 + w * 32;   // this wave's 32 o-columns

    // ---- W fragments in registers: wv[j][kk], 16 x bf16x8 = 64 VGPR ----
    const __bf16* wp0 = wt + ((size_t)v * NO + obase + lr) * NK + lg * 8;
    const __bf16* wp1 = wp0 + (size_t)16 * NK;
    bf16x8 wv0[8], wv1[8];
#pragma unroll
    for (int kk = 0; kk < 8; ++kk) {
        wv0[kk] = *(const bf16x8*)(wp0 + kk * 32);
        wv1[kk] = *(const bf16x8*)(wp1 + kk * 32);
    }

    // bias, pre-scaled by 256, laid out per C-fragment (o = obase+j*16+lg*4+r)
    const float* bg = bias + (size_t)v * NO + obase + lg * 4;
    f32x4 bb0 = *(const f32x4*)(bg);
    f32x4 bb1 = *(const f32x4*)(bg + 16);
#pragma unroll
    for (int r = 0; r < 4; ++r) { bb0[r] *= 256.0f; bb1[r] *= 256.0f; }

    // per-lane x source / out dest pointers (advance by 16 rows per m-tile)
    const float* xp = x   + ((size_t)v * NB + (size_t)mb * 64 + lr) * NK + lg * 8;
    float*       op = out + ((size_t)v * NB + (size_t)mb * 64 + lr) * NO + obase + lg * 4;

#pragma unroll
    for (int it = 0; it < 4; ++it) {
        const float* xi = xp + (size_t)it * 16 * NK;
        // x fragment loads: 16 x f32x4; per instr: 16 rows x 16B (64B segments
        // across 4 lanes) -- L1-friendly; 16 KB in flight per wave
        f32x4 lo[8], hi[8];
#pragma unroll
        for (int kk = 0; kk < 8; ++kk) {
            lo[kk] = *(const f32x4*)(xi + kk * 32);
            hi[kk] = *(const f32x4*)(xi + kk * 32 + 4);
        }
        f32x4 acc0 = {0.f, 0.f, 0.f, 0.f};
        f32x4 acc1 = {0.f, 0.f, 0.f, 0.f};
#pragma unroll
        for (int kk = 0; kk < 8; ++kk) {
            bf16x8 bf;
#pragma unroll
            for (int e = 0; e < 4; ++e) {
                bf[e]     = (__bf16)lo[kk][e];
                bf[e + 4] = (__bf16)hi[kk][e];
            }
            // A-operand := W frag (rows = o), B-operand := x frag (cols = batch)
            acc0 = mfma16(wv0[kk], bf, acc0);
            acc1 = mfma16(wv1[kk], bf, acc1);
        }
        // epilogue: batch = mb*64 + it*16 + lr, o = obase + j*16 + lg*4 + r
        float* oi = op + (size_t)it * 16 * NO;
        f32x4 r0, r1;
#pragma unroll
        for (int r = 0; r < 4; ++r) {
            r0[r] = softplus_f(acc0[r] + bb0[r]);
            r1[r] = softplus_f(acc1[r] + bb1[r]);
        }
        *(f32x4*)(oi)      = r0;
        *(f32x4*)(oi + 16) = r1;
    }
}

extern "C" void kernel_launch(void* const* d_in, const int* in_sizes, int n_in,
                              void* d_out, int out_size, void* d_ws, size_t ws_size,
                              hipStream_t stream) {
    const float* x  = (const float*)d_in[0];
    const float* w  = (const float*)d_in[1];
    const float* b  = (const float*)d_in[2];
    float* out      = (float*)d_out;
    __bf16* wt      = (__bf16*)d_ws;   // 32*256*256*2 B = 4 MB scratch

    // 1) transpose+convert W -> Wt bf16
    hipLaunchKernelGGL(prep_wt_kernel, dim3(1024), dim3(256), 0, stream, w, wt);
    // 2) streaming grouped GEMM + bias + softplus (no LDS, no barriers)
    hipLaunchKernelGGL(mv_dense_kernel, dim3(NV * 64 * 2), dim3(256), 0, stream,
                       x, wt, b, out);
}

// Round 6
// 66.377 us; speedup vs baseline: 2.5628x; 2.5628x over previous
//
#include <hip/hip_runtime.h>
#include <stdint.h>
#include <math.h>

// Problem constants
#define NV 32      // num_vari (groups)
#define NB 4096    // batch
#define NK 256     // 2*dim_per_vari (contraction)
#define NO 256     // dim_to (output features)

#define TROWS 16   // rows per m-tile
#define NTILE 16   // m-tiles per block (slab = 256 rows)

typedef __bf16 bf16x8 __attribute__((ext_vector_type(8)));
typedef float  f32x4  __attribute__((ext_vector_type(4)));

__device__ __forceinline__ f32x4 mfma16(bf16x8 a, bf16x8 b, f32x4 c) {
    return __builtin_amdgcn_mfma_f32_16x16x32_bf16(a, b, c, 0, 0, 0);
}

__device__ __forceinline__ float softplus_f(float z) {
    return fmaxf(z, 0.0f) + __logf(1.0f + __expf(-fabsf(z)));
}

__device__ __forceinline__ void gload_lds16(const void* g, void* l) {
    // async global->LDS DMA, 16 B/lane; LDS dest = wave-uniform base + lane*16
    __builtin_amdgcn_global_load_lds((const __attribute__((address_space(1))) uint32_t*)g,
                                     (__attribute__((address_space(3))) uint32_t*)l,
                                     16, 0, 0);
}

// ---------------------------------------------------------------------------
// prep: W[v][k][o] fp32  ->  Wt[v][o][k] bf16  (transpose + convert, 4 MB)
__global__ __launch_bounds__(256)
void prep_wt_kernel(const float* __restrict__ w, __bf16* __restrict__ wt) {
    const int id = blockIdx.x * 256 + threadIdx.x;   // 262144
    const int o  = id & 255;
    const int kc = (id >> 8) & 31;
    const int v  = id >> 13;
    const float* src = w + ((size_t)v * NK + (size_t)kc * 8) * NO + o;
    bf16x8 r;
#pragma unroll
    for (int j = 0; j < 8; ++j) r[j] = (__bf16)src[(size_t)j * NO];
    *(bf16x8*)(wt + ((size_t)v * NO + o) * NK + kc * 8) = r;
}

// ---------------------------------------------------------------------------
// main: streaming DMA pipeline. W in registers (loop-invariant across a real
// loop), x tiles triple-buffered in LDS via global_load_lds, raw s_barrier +
// counted vmcnt(4) -> 2 tiles always in flight; one compute phase per tile.
__global__ __launch_bounds__(512, 4)
void mv_dense_kernel(const float* __restrict__ x, const __bf16* __restrict__ wt,
                     const float* __restrict__ bias, float* __restrict__ out) {
    // 16B-chunk XOR swizzle within each row: phys = logical ^ (row & 7)
    __shared__ float Xs[3][TROWS][NK];   // 48 KB

    const int t    = threadIdx.x;
    const int w    = t >> 6;      // wave 0..7 -> o-columns [w*32, w*32+32)
    const int lane = t & 63;
    const int lr   = lane & 15;
    const int lg   = lane >> 4;

    // XCD-chunked: 512 blocks = 8 XCD x 64; each XCD owns 4 v's (Wt 512KB/L2)
    const int bid  = blockIdx.x;
    const int lb   = (bid & 7) * 64 + (bid >> 3);
    const int v    = lb >> 4;     // 0..31
    const int slab = lb & 15;     // 0..15 -> 256 rows each

    const float*  xg = x    + ((size_t)v * NB + (size_t)slab * 256) * NK;
    float*        og = out  + ((size_t)v * NB + (size_t)slab * 256) * NO;

    // ---- W fragments in registers (issued first; L2-resident) ----
    const __bf16* wp0 = wt + ((size_t)v * NO + w * 32 + lr) * NK + lg * 8;
    const __bf16* wp1 = wp0 + (size_t)16 * NK;
    bf16x8 wv0[8], wv1[8];
#pragma unroll
    for (int kk = 0; kk < 8; ++kk) {
        wv0[kk] = *(const bf16x8*)(wp0 + kk * 32);
        wv1[kk] = *(const bf16x8*)(wp1 + kk * 32);
    }

    // bias, pre-scaled by 256, laid out per C-fragment (o = w*32 + j*16 + lg*4 + r)
    const float* bg = bias + (size_t)v * NO + w * 32 + lg * 4;
    f32x4 bb0 = *(const f32x4*)bg;
    f32x4 bb1 = *(const f32x4*)(bg + 16);
#pragma unroll
    for (int r = 0; r < 4; ++r) { bb0[r] *= 256.0f; bb1[r] *= 256.0f; }

    // stage tile -> buf: wave w fills rows w and w+8 (phys chunk = lane),
    // global source pre-inverse-swizzled: logical chunk = lane ^ (row & 7)
    const int cl = lane ^ (w & 7);           // same for rows w and w+8
    auto stage = [&](int tile, int buf) {
        const float* s0 = xg + (size_t)(tile * TROWS + w)     * NK + cl * 4;
        const float* s1 = xg + (size_t)(tile * TROWS + w + 8) * NK + cl * 4;
        gload_lds16(s0, (void*)&Xs[buf][w][0]);
        gload_lds16(s1, (void*)&Xs[buf][w + 8][0]);
    };

    // fragment-read byte offsets (within one tile): row lr, logical floats
    // 32*kk + 8*lg (+4); phys chunk = logical ^ (lr&7)
    const int b0c   = (2 * lg) ^ (lr & 7);
    const int aoff0 = lr * 1024 + b0c * 16;
    const int aoff1 = lr * 1024 + (b0c ^ 1) * 16;

    auto compute = [&](int tile, int buf) {
        const char* tb = (const char*)&Xs[buf][0][0];
        f32x4 acc0 = {0.f, 0.f, 0.f, 0.f};
        f32x4 acc1 = {0.f, 0.f, 0.f, 0.f};
#pragma unroll
        for (int kk = 0; kk < 8; ++kk) {
            f32x4 lo = *(const f32x4*)(tb + aoff0 + kk * 128);
            f32x4 hi = *(const f32x4*)(tb + aoff1 + kk * 128);
            bf16x8 bf;
#pragma unroll
            for (int e = 0; e < 4; ++e) { bf[e] = (__bf16)lo[e]; bf[e + 4] = (__bf16)hi[e]; }
            // A-operand := W frag (rows = o), B-operand := x frag (cols = batch)
            acc0 = mfma16(wv0[kk], bf, acc0);
            acc1 = mfma16(wv1[kk], bf, acc1);
        }
        // batch row = tile*16 + lr, o = w*32 + {0,16} + lg*4 + r
        float* o = og + (size_t)(tile * TROWS + lr) * NO + w * 32 + lg * 4;
        f32x4 r0, r1;
#pragma unroll
        for (int r = 0; r < 4; ++r) {
            r0[r] = softplus_f(acc0[r] + bb0[r]);
            r1[r] = softplus_f(acc1[r] + bb1[r]);
        }
        *(f32x4*)o        = r0;
        *(f32x4*)(o + 16) = r1;
    };

    // ---- pipeline prologue: 2 tiles in flight ----
    stage(0, 0);
    stage(1, 1);

    // peeled iter 0: drain prologue (W + bias + tile0; tile1 may complete too)
    asm volatile("s_waitcnt vmcnt(0)" ::: "memory");
    __builtin_amdgcn_s_barrier();
    __builtin_amdgcn_sched_barrier(0);
    stage(2, 2);
    compute(0, 0);

    // steady state: per iter exactly {2 gload_lds + 2 stores} issued; vmcnt(4)
    // forces tile tt complete while leaving tile tt+1 (+ last stores) in flight
#pragma unroll 1
    for (int tt = 1; tt < NTILE; ++tt) {
        asm volatile("s_waitcnt vmcnt(4)" ::: "memory");
        __builtin_amdgcn_s_barrier();
        __builtin_amdgcn_sched_barrier(0);
        if (tt + 2 < NTILE) stage(tt + 2, (tt + 2) % 3);   // overwrites buf of tt-1 (done)
        compute(tt, tt % 3);
    }
}

extern "C" void kernel_launch(void* const* d_in, const int* in_sizes, int n_in,
                              void* d_out, int out_size, void* d_ws, size_t ws_size,
                              hipStream_t stream) {
    const float* x  = (const float*)d_in[0];
    const float* w  = (const float*)d_in[1];
    const float* b  = (const float*)d_in[2];
    float* out      = (float*)d_out;
    __bf16* wt      = (__bf16*)d_ws;   // 4 MB scratch

    hipLaunchKernelGGL(prep_wt_kernel, dim3(1024), dim3(256), 0, stream, w, wt);
    // 512 blocks x 512 thr: exactly 2 blocks/CU resident, whole grid co-resident
    hipLaunchKernelGGL(mv_dense_kernel, dim3(512), dim3(512), 0, stream,
                       x, wt, b, out);
}